// Round 7
// baseline (399.797 us; speedup 1.0000x reference)
//
#include <hip/hip_runtime.h>
#include <math.h>

#define IN_F 128
#define HID 64
#define N_NODES 100000
#define N_EDGES 1000000
#define SCAN_BLOCKS 98   // ceil(N_NODES / 1024)

typedef __attribute__((ext_vector_type(8))) short bf16x8;
typedef __attribute__((ext_vector_type(4))) float f32x4;
typedef __attribute__((ext_vector_type(4))) unsigned short u16x4;

// round-to-nearest-even fp32 -> bf16 (inputs finite)
static __device__ __forceinline__ short f2bf(float f) {
    union { float f; unsigned u; } v; v.f = f;
    unsigned r = v.u + 0x7fffu + ((v.u >> 16) & 1u);
    return (short)(r >> 16);
}
static __device__ __forceinline__ unsigned short f2bfu(float f) {
    union { float f; unsigned u; } v; v.f = f;
    unsigned r = v.u + 0x7fffu + ((v.u >> 16) & 1u);
    return (unsigned short)(r >> 16);
}
static __device__ __forceinline__ float bf2f(unsigned short u) {
    union { unsigned u; float f; } v; v.u = ((unsigned)u) << 16; return v.f;
}

// ---------------------------------------------------------------------------
// Pack W ([128][64] fp32) into bf16 B-fragment layout:
//   entry (c*4+s)*64 + l  holds 8 bf16 = W[k][16c+n], k=32s+8q+j, l=16q+n
// ---------------------------------------------------------------------------
__global__ __launch_bounds__(256)
void pack_w_kernel(const float* __restrict__ W, short* __restrict__ Wpk)
{
    int i = blockIdx.x * 256 + threadIdx.x;   // 1024 entries
    if (i < 1024) {
        int l = i & 63, cs = i >> 6;
        int c = cs >> 2, s = cs & 3;
        int n = l & 15, q = l >> 4;
        short v[8];
        #pragma unroll
        for (int j = 0; j < 8; ++j)
            v[j] = f2bf(W[(32 * s + 8 * q + j) * HID + 16 * c + n]);
        *(bf16x8*)&Wpk[(size_t)i * 8] = *(const bf16x8*)v;
    }
}

// ---------------------------------------------------------------------------
// Fused 3x GEMM via bf16 MFMA, zero LDS. 4 waves/block, each wave does TWO
// 16-row tiles (32 rows) x 64 cols -> 128 rows/block. All HBM A-loads are
// issued before any MFMA (memory-level parallelism); B-frags come from
// pre-packed Wpk (identical addresses for all waves -> L1/L2 broadcast).
//   C/D: col=l&15, row=4*quad+reg  [m89/m91 verified]
// which==0 -> H0 fp32 + p0 ; which==1/2 -> H bf16 + q1/q2
// ---------------------------------------------------------------------------
__global__ __launch_bounds__(256)
void lin_att_mfma(const float* __restrict__ feat0, const float* __restrict__ feat1,
                  const float* __restrict__ feat2,
                  const short* __restrict__ Wpk, const float* __restrict__ b_feat,
                  const float* __restrict__ W_att,
                  float* __restrict__ H0,
                  unsigned short* __restrict__ H1b, unsigned short* __restrict__ H2b,
                  float* __restrict__ p0, float* __restrict__ q1, float* __restrict__ q2)
{
    const int which = blockIdx.y;
    const float* feat = (which == 0) ? feat0 : (which == 1) ? feat1 : feat2;
    float* sOut = (which == 0) ? p0 : (which == 1) ? q1 : q2;
    unsigned short* Hb = (which == 1) ? H1b : H2b;

    const int t  = threadIdx.x;
    const int wv = t >> 6;
    const int l  = t & 63;
    const int n  = l & 15;
    const int q  = l >> 4;
    const int rowBase = blockIdx.x * 128 + wv * 32;   // tiles at +0 and +16

    // ---- issue ALL A-loads first (16 x dwordx4 per thread, HBM) ----
    int r0 = rowBase + n;       r0 = (r0 < N_NODES) ? r0 : (N_NODES - 1);
    int r1 = rowBase + 16 + n;  r1 = (r1 < N_NODES) ? r1 : (N_NODES - 1);
    const float* base0 = &feat[(size_t)r0 * IN_F + 8 * q];
    const float* base1 = &feat[(size_t)r1 * IN_F + 8 * q];

    float4 xa[2][4][2];
    #pragma unroll
    for (int s = 0; s < 4; ++s) {
        xa[0][s][0] = *(const float4*)(base0 + 32 * s);
        xa[0][s][1] = *(const float4*)(base0 + 32 * s + 4);
        xa[1][s][0] = *(const float4*)(base1 + 32 * s);
        xa[1][s][1] = *(const float4*)(base1 + 32 * s + 4);
    }

    f32x4 acc[2][4];
    #pragma unroll
    for (int c = 0; c < 4; ++c) {
        float bv = b_feat[16 * c + n];
        acc[0][c][0] = bv; acc[0][c][1] = bv; acc[0][c][2] = bv; acc[0][c][3] = bv;
        acc[1][c][0] = bv; acc[1][c][1] = bv; acc[1][c][2] = bv; acc[1][c][3] = bv;
    }

    #pragma unroll
    for (int s = 0; s < 4; ++s) {
        bf16x8 a0, a1;
        #pragma unroll
        for (int h = 0; h < 2; ++h) {
            a0[4 * h + 0] = f2bf(xa[0][s][h].x); a0[4 * h + 1] = f2bf(xa[0][s][h].y);
            a0[4 * h + 2] = f2bf(xa[0][s][h].z); a0[4 * h + 3] = f2bf(xa[0][s][h].w);
            a1[4 * h + 0] = f2bf(xa[1][s][h].x); a1[4 * h + 1] = f2bf(xa[1][s][h].y);
            a1[4 * h + 2] = f2bf(xa[1][s][h].z); a1[4 * h + 3] = f2bf(xa[1][s][h].w);
        }
        #pragma unroll
        for (int c = 0; c < 4; ++c) {
            bf16x8 B = *(const bf16x8*)&Wpk[((c * 4 + s) * 64 + l) * 8];
            acc[0][c] = __builtin_amdgcn_mfma_f32_16x16x32_bf16(a0, B, acc[0][c], 0, 0, 0);
            acc[1][c] = __builtin_amdgcn_mfma_f32_16x16x32_bf16(a1, B, acc[1][c], 0, 0, 0);
        }
    }

    // ---- epilogue: store H (+ fused attention scalar) for both tiles ----
    #pragma unroll
    for (int tile = 0; tile < 2; ++tile) {
        const int tBase = rowBase + 16 * tile;
        float part[4] = {0.f, 0.f, 0.f, 0.f};
        #pragma unroll
        for (int c = 0; c < 4; ++c) {
            int col = 16 * c + n;
            float a0 = W_att[col], a1 = W_att[HID + col];
            float ae = (which == 0) ? (a0 + a1 * (1.0f / 3.0f)) : (a1 * (1.0f / 3.0f));
            #pragma unroll
            for (int r = 0; r < 4; ++r) {
                int row = tBase + 4 * q + r;
                if (row < N_NODES) {
                    if (which == 0) H0[(size_t)row * HID + col] = acc[tile][c][r];
                    else            Hb[(size_t)row * HID + col] = f2bfu(acc[tile][c][r]);
                }
                part[r] = fmaf(acc[tile][c][r], ae, part[r]);
            }
        }
        #pragma unroll
        for (int r = 0; r < 4; ++r) {
            float p = part[r];
            p += __shfl_xor(p, 1, 64);
            p += __shfl_xor(p, 2, 64);
            p += __shfl_xor(p, 4, 64);
            p += __shfl_xor(p, 8, 64);
            int row = tBase + 4 * q + r;
            if (n == 0 && row < N_NODES) sOut[row] = p;
        }
    }
}

// ---------------------------------------------------------------------------
// CSR build
// ---------------------------------------------------------------------------
__global__ __launch_bounds__(256)
void hist_kernel(const int* __restrict__ e0a, int* __restrict__ counts)
{
    int i = blockIdx.x * 256 + threadIdx.x;
    if (i < N_EDGES / 4) {
        int4 e = ((const int4*)e0a)[i];
        atomicAdd(&counts[e.x], 1);
        atomicAdd(&counts[e.y], 1);
        atomicAdd(&counts[e.z], 1);
        atomicAdd(&counts[e.w], 1);
    }
}

__global__ __launch_bounds__(256)
void scan1_kernel(const int* __restrict__ counts, int* __restrict__ offsets,
                  int* __restrict__ blockSums)
{
    __shared__ int s[256];
    int t = threadIdx.x;
    int base = blockIdx.x * 1024 + t * 4;
    int c0 = (base + 0 < N_NODES) ? counts[base + 0] : 0;
    int c1 = (base + 1 < N_NODES) ? counts[base + 1] : 0;
    int c2 = (base + 2 < N_NODES) ? counts[base + 2] : 0;
    int c3 = (base + 3 < N_NODES) ? counts[base + 3] : 0;
    int tsum = c0 + c1 + c2 + c3;
    s[t] = tsum;
    __syncthreads();
    for (int off = 1; off < 256; off <<= 1) {
        int v = (t >= off) ? s[t - off] : 0;
        __syncthreads();
        s[t] += v;
        __syncthreads();
    }
    int excl = s[t] - tsum;
    if (base + 0 < N_NODES) offsets[base + 0] = excl;
    if (base + 1 < N_NODES) offsets[base + 1] = excl + c0;
    if (base + 2 < N_NODES) offsets[base + 2] = excl + c0 + c1;
    if (base + 3 < N_NODES) offsets[base + 3] = excl + c0 + c1 + c2;
    if (t == 255) blockSums[blockIdx.x] = s[255];
}

__global__ __launch_bounds__(128)
void scan2_kernel(int* __restrict__ blockSums)
{
    __shared__ int s[128];
    int t = threadIdx.x;
    int v = (t < SCAN_BLOCKS) ? blockSums[t] : 0;
    s[t] = v;
    __syncthreads();
    for (int off = 1; off < 128; off <<= 1) {
        int u = (t >= off) ? s[t - off] : 0;
        __syncthreads();
        s[t] += u;
        __syncthreads();
    }
    if (t < SCAN_BLOCKS) blockSums[t] = s[t] - v;   // exclusive
}

__global__ __launch_bounds__(256)
void scan3_kernel(int* __restrict__ offsets, int* __restrict__ cursor,
                  const int* __restrict__ blockSums)
{
    int t = threadIdx.x;
    int base = blockIdx.x * 1024 + t * 4;
    int add = blockSums[blockIdx.x];
    #pragma unroll
    for (int k = 0; k < 4; ++k) {
        int i = base + k;
        if (i < N_NODES) {
            int v = offsets[i] + add;
            offsets[i] = v;
            cursor[i] = v;
        }
    }
}

// scatter: pure counting-sort placement of (e1,e2) as an 8B record.
// Score is recomputed in aggregate (tables are L2-hot there).
__global__ __launch_bounds__(256)
void scatter_kernel(const int* __restrict__ e0a, const int* __restrict__ e1a,
                    const int* __restrict__ e2a,
                    int* __restrict__ cursor, int2* __restrict__ rec)
{
    int i = blockIdx.x * 256 + threadIdx.x;
    if (i < N_EDGES) {
        int e0 = e0a[i], e1 = e1a[i], e2 = e2a[i];
        int pos = atomicAdd(&cursor[e0], 1);
        rec[pos] = make_int2(e1, e2);
    }
}

// ---------------------------------------------------------------------------
// Aggregate (CSR, fused): 16 lanes/node, zero atomics, bf16 gathers.
// Recomputes w_e = exp(tanh(p0[n]+q1[e1]+q2[e2]+b)) from L2-hot tables.
// out[n] = bias + H0[n]/3 + (1/(3*sum_w)) * sum_e w_e*(H1[e1]+H2[e2])
// (tanh in [-1,1] => exp safe; softmax shift-invariance => no segment-max)
// ---------------------------------------------------------------------------
__global__ __launch_bounds__(256)
void aggregate_csr_kernel(const int* __restrict__ offsets, const int* __restrict__ counts,
                          const int2* __restrict__ rec,
                          const float* __restrict__ p0, const float* __restrict__ q1,
                          const float* __restrict__ q2, const float* __restrict__ b_att,
                          const float* __restrict__ H0,
                          const unsigned short* __restrict__ H1b,
                          const unsigned short* __restrict__ H2b,
                          const float* __restrict__ bias,
                          float* __restrict__ out)
{
    int gid  = blockIdx.x * 256 + threadIdx.x;
    int node = gid >> 4;
    int sub  = gid & 15;
    if (node >= N_NODES) return;

    int start = offsets[node];
    int cnt   = counts[node];
    float pe  = p0[node] + b_att[0];

    float denom = 0.0f;
    float ax = 0.0f, ay = 0.0f, az = 0.0f, aw = 0.0f;
    for (int j = 0; j < cnt; ++j) {
        int2 r = rec[start + j];                   // broadcast across 16 lanes
        float x = pe + q1[r.x] + q2[r.y];
        float w = __expf(tanhf(x));
        u16x4 h1 = *(const u16x4*)&H1b[(size_t)r.x * HID + 4 * sub];
        u16x4 h2 = *(const u16x4*)&H2b[(size_t)r.y * HID + 4 * sub];
        denom += w;
        ax = fmaf(w, bf2f(h1.x) + bf2f(h2.x), ax);
        ay = fmaf(w, bf2f(h1.y) + bf2f(h2.y), ay);
        az = fmaf(w, bf2f(h1.z) + bf2f(h2.z), az);
        aw = fmaf(w, bf2f(h1.w) + bf2f(h2.w), aw);
    }

    float4 h0 = *(const float4*)&H0[(size_t)node * HID + 4 * sub];
    float4 bv = *(const float4*)&bias[4 * sub];
    float third = (cnt > 0) ? (1.0f / 3.0f) : 0.0f;
    float inv   = (cnt > 0) ? 1.0f / (3.0f * denom) : 0.0f;

    float4 o;
    o.x = bv.x + third * h0.x + inv * ax;
    o.y = bv.y + third * h0.y + inv * ay;
    o.z = bv.z + third * h0.z + inv * az;
    o.w = bv.w + third * h0.w + inv * aw;
    *(float4*)&out[(size_t)node * HID + 4 * sub] = o;
}

// ---------------------------------------------------------------------------
extern "C" void kernel_launch(void* const* d_in, const int* in_sizes, int n_in,
                              void* d_out, int out_size, void* d_ws, size_t ws_size,
                              hipStream_t stream)
{
    const float* feat0  = (const float*)d_in[0];
    const float* feat1  = (const float*)d_in[1];
    const float* feat2  = (const float*)d_in[2];
    const int*   edge0  = (const int*)d_in[3];
    const int*   edge1  = (const int*)d_in[4];
    const int*   edge2  = (const int*)d_in[5];
    const float* W_feat = (const float*)d_in[6];
    const float* b_feat = (const float*)d_in[7];
    const float* W_att  = (const float*)d_in[8];
    const float* b_att  = (const float*)d_in[9];
    const float* bias   = (const float*)d_in[10];
    float* out = (float*)d_out;

    // workspace layout (16B-aligned chunks first)
    int2*   rec  = (int2*)d_ws;                            // 1M int2 = 8 MB
    short*  Wpk  = (short*)(rec + N_EDGES);                // 8192 shorts (16 KB)
    float*  H0   = (float*)(Wpk + 8192);                   // 6.4M floats (25.6 MB)
    unsigned short* H1b = (unsigned short*)(H0 + (size_t)N_NODES * HID); // 12.8 MB
    unsigned short* H2b = H1b + (size_t)N_NODES * HID;                   // 12.8 MB
    float*  p0   = (float*)(H2b + (size_t)N_NODES * HID);
    float*  q1   = p0 + N_NODES;
    float*  q2   = q1 + N_NODES;
    int* counts    = (int*)(q2 + N_NODES);
    int* offsets   = counts + N_NODES;
    int* cursor    = offsets + N_NODES;
    int* blockSums = cursor + N_NODES;                     // 128
    // total ~62 MB

    (void)hipMemsetAsync(counts, 0, N_NODES * sizeof(int), stream);

    dim3 blk(256);
    pack_w_kernel<<<4, blk, 0, stream>>>(W_feat, Wpk);

    dim3 gemmGrid((N_NODES + 127) / 128, 3);
    lin_att_mfma<<<gemmGrid, blk, 0, stream>>>(feat0, feat1, feat2,
                                               Wpk, b_feat, W_att,
                                               H0, H1b, H2b, p0, q1, q2);

    hist_kernel<<<(N_EDGES / 4 + 255) / 256, blk, 0, stream>>>(edge0, counts);
    scan1_kernel<<<SCAN_BLOCKS, blk, 0, stream>>>(counts, offsets, blockSums);
    scan2_kernel<<<1, 128, 0, stream>>>(blockSums);
    scan3_kernel<<<SCAN_BLOCKS, blk, 0, stream>>>(offsets, cursor, blockSums);

    scatter_kernel<<<(N_EDGES + 255) / 256, blk, 0, stream>>>(
        edge0, edge1, edge2, cursor, rec);

    aggregate_csr_kernel<<<((size_t)N_NODES * 16 + 255) / 256, blk, 0, stream>>>(
        offsets, counts, rec, p0, q1, q2, b_att, H0, H1b, H2b, bias, out);
}